// Round 6
// baseline (200.642 us; speedup 1.0000x reference)
//
#include <hip/hip_runtime.h>

// Problem constants
#define G   128
#define A   100
#define WIN 10
#define FD  16
#define H   128
#define NROWS (G*A)          // 12800
#define K1  (WIN*FD)         // 160

typedef __attribute__((ext_vector_type(8))) short short8;
typedef __attribute__((ext_vector_type(4))) short short4v;
typedef __attribute__((ext_vector_type(4))) float floatx4;

struct BfPair { short h, l; };

__device__ inline unsigned short f2bf(float f) {   // RNE fp32 -> bf16
    unsigned u = __float_as_uint(f);
    u += 0x7fff + ((u >> 16) & 1);
    return (unsigned short)(u >> 16);
}
__device__ inline float bf2f(unsigned short h) {
    return __uint_as_float(((unsigned)h) << 16);
}
__device__ inline BfPair split1(float v) {
    BfPair p;
    unsigned short hb = f2bf(v);
    p.h = (short)hb;
    p.l = (short)f2bf(v - bf2f(hb));
    return p;
}

// ---------------------------------------------------------------------------
// k_prep: pre-split W1/W2/W3 into bf16 hi/lo planes, [n=128][k pad-stride 160],
// and pack conv weights into wpack[c][8] = {w0,w1,w2,b1, v0,v1,v2, cb2}.
// Runs every launch (ws is re-poisoned).
// ---------------------------------------------------------------------------
__global__ __launch_bounds__(256) void k_prep(const float* __restrict__ W1,
                                              const float* __restrict__ W2,
                                              const float* __restrict__ W3,
                                              const float* __restrict__ cw1,
                                              const float* __restrict__ cb1,
                                              const float* __restrict__ cw2,
                                              const float* __restrict__ cb2,
                                              short* __restrict__ Wh,
                                              short* __restrict__ Wl,
                                              float* __restrict__ wpack) {
    const int b = blockIdx.x, t = threadIdx.x;
    if (b < 26) {
        int l, kc, K;
        const float* Wsrc;
        if (b < 10)      { l = 0; kc = b;      K = K1; Wsrc = W1; }
        else if (b < 18) { l = 1; kc = b - 10; K = H;  Wsrc = W2; }
        else             { l = 2; kc = b - 18; K = H;  Wsrc = W3; }
        short* dh = Wh + l * 128 * 160;
        short* dl = Wl + l * 128 * 160;
        for (int e = t; e < 16 * 128; e += 256) {
            int k = kc * 16 + (e >> 7), n = e & 127;
            BfPair p = split1(Wsrc[(size_t)k * H + n]);
            dh[n * 160 + k] = p.h;
            dl[n * 160 + k] = p.l;
        }
        (void)K;
    } else {
        for (int e = t; e < 1024; e += 256) {
            int c = e >> 3, s = e & 7;
            float v;
            if (s < 3)       v = cw1[3 * c + s];
            else if (s == 3) v = cb1[c];
            else if (s < 7)  v = cw2[3 * c + (s - 4)];
            else             v = cb2[0];
            wpack[e] = v;
        }
    }
}

// ---------------------------------------------------------------------------
// k_nadj: per-group normalized adjacency -> split-bf16 S planes
//   S[g][m=i (pad 112)][k=j (pad 128)], zeros for i>=100 or j>=100.
// ---------------------------------------------------------------------------
__global__ __launch_bounds__(256) void k_nadj(const float* __restrict__ x,
                                              short* __restrict__ Sh,
                                              short* __restrict__ Sl) {
    __shared__ float xcT[WIN][104];
    __shared__ float invn[A];
    __shared__ float adjs[A][101];
    __shared__ float dinv[A];
    const int g = blockIdx.x;
    const int t = threadIdx.x;

    for (int idx = t; idx < A * WIN; idx += 256) {
        int a = idx / WIN, w = idx % WIN;
        xcT[w][a] = x[((g * A + a) * WIN + w) * FD + (FD - 1)];
    }
    __syncthreads();
    if (t < A) {
        float m = 0.f;
        #pragma unroll
        for (int w = 0; w < WIN; w++) m += xcT[w][t];
        m *= (1.0f / WIN);
        float ss = 0.f;
        #pragma unroll
        for (int w = 0; w < WIN; w++) {
            float v = xcT[w][t] - m;
            xcT[w][t] = v;
            ss += v * v;
        }
        invn[t] = rsqrtf(ss);
    }
    __syncthreads();
    for (int tt2 = t; tt2 < 2500; tt2 += 256) {
        int ti = tt2 / 50, tj = tt2 % 50;
        int i0 = 2 * ti, j0v = 2 * tj;
        float d00 = 0.f, d01 = 0.f, d10 = 0.f, d11 = 0.f;
        #pragma unroll
        for (int w = 0; w < WIN; w++) {
            float2 xi = *(const float2*)&xcT[w][i0];
            float2 xj = *(const float2*)&xcT[w][j0v];
            d00 = fmaf(xi.x, xj.x, d00); d01 = fmaf(xi.x, xj.y, d01);
            d10 = fmaf(xi.y, xj.x, d10); d11 = fmaf(xi.y, xj.y, d11);
        }
        float ii0 = invn[i0], ii1 = invn[i0 + 1];
        float ij0 = invn[j0v], ij1 = invn[j0v + 1];
        float e = (ti == tj) ? 1.f : 0.f;
        adjs[i0][j0v]         = 1.f - fabsf(d00 * ii0 * ij0) + e;
        adjs[i0][j0v + 1]     = 1.f - fabsf(d01 * ii0 * ij1);
        adjs[i0 + 1][j0v]     = 1.f - fabsf(d10 * ii1 * ij0);
        adjs[i0 + 1][j0v + 1] = 1.f - fabsf(d11 * ii1 * ij1) + e;
    }
    __syncthreads();
    if (t < A) {
        float s = 0.f;
        for (int j = 0; j < A; j++) s += adjs[t][j];
        dinv[t] = rsqrtf(s);
    }
    __syncthreads();
    short* sh = Sh + (size_t)g * 112 * 128;
    short* sl = Sl + (size_t)g * 112 * 128;
    for (int idx = t; idx < 112 * 128; idx += 256) {
        int i = idx >> 7, k = idx & 127;
        float v = (i < A && k < A) ? dinv[i] * adjs[i][k] * dinv[k] : 0.f;
        BfPair p = split1(v);
        sh[idx] = p.h;
        sl[idx] = p.l;
    }
}

// ---------------------------------------------------------------------------
// k_layer: Z[g,:,cbase:+32] = relu(S @ (X @ W[:,cbase:+32]) + b)
// Grid (G, 4 n-quarters) = 512 blocks (2/CU), 256 thr (4 waves).
// Wave w: m-tiles {2w,2w+1} (w<3) or {6}; 2 n-tiles of 16 each.
// W frags: direct global (pre-split). S frags: direct global (pre-split).
// Only X (fp32) converts through LDS. Y tile lives in LDS (stride 136).
// ---------------------------------------------------------------------------
__global__ __launch_bounds__(256) void k_layer(const short* __restrict__ Sh,
                                               const short* __restrict__ Sl,
                                               const short* __restrict__ Whg,
                                               const short* __restrict__ Wlg,
                                               const float* __restrict__ X,
                                               const float* __restrict__ bias,
                                               float* __restrict__ Z, int K) {
    __shared__ short Xh[112 * 40], Xl[112 * 40];   // 17.9 KB
    __shared__ short Yh[32 * 136], Yl[32 * 136];   // 17.4 KB
    const int g = blockIdx.x;
    const int cbase = blockIdx.y * 32;
    const int t = threadIdx.x;
    const int w = t >> 6, lane = t & 63;
    const int quad = lane >> 4, r16 = lane & 15;
    const int nm = (w < 3) ? 2 : 1;     // m-tiles this wave
    const int m0 = 2 * w;               // first m-tile index

    // zero X pad rows 100..111 (k cols 0..31), Y pad k rows 112..127
    for (int e = t; e < 384; e += 256) {
        int r = 100 + e / 32, c = e % 32;
        Xh[r * 40 + c] = 0; Xl[r * 40 + c] = 0;
    }
    for (int e = t; e < 512; e += 256) {
        int n = e >> 4, k = 112 + (e & 15);
        Yh[n * 136 + k] = 0; Yl[n * 136 + k] = 0;
    }

    floatx4 acc[2][2];
    #pragma unroll
    for (int i = 0; i < 2; i++)
        #pragma unroll
        for (int j = 0; j < 2; j++) acc[i][j] = (floatx4)0.f;

    // ---- phase A: Y = X @ W(quarter) ----
    const float* Xg = X + (size_t)g * A * K;
    const int nch = K >> 5;
    for (int c = 0; c < nch; c++) {
        const int k0 = c << 5;
        __syncthreads();   // protect Xh/Xl from previous chunk's readers
        for (int e = t; e < 400; e += 256) {
            int r = e >> 2, q = e & 3;
            const float* gp = Xg + (size_t)r * K + k0 + q * 8;
            float4 f0 = *(const float4*)gp;
            float4 f1 = *(const float4*)(gp + 4);
            float v[8] = {f0.x, f0.y, f0.z, f0.w, f1.x, f1.y, f1.z, f1.w};
            short8 hh, ll;
            #pragma unroll
            for (int i = 0; i < 8; i++) {
                BfPair p = split1(v[i]);
                hh[i] = p.h; ll[i] = p.l;
            }
            *(short8*)&Xh[r * 40 + q * 8] = hh;
            *(short8*)&Xl[r * 40 + q * 8] = ll;
        }
        __syncthreads();
        short8 bh[2], bl[2];
        #pragma unroll
        for (int nt = 0; nt < 2; nt++) {
            size_t wo = (size_t)(cbase + nt * 16 + r16) * 160 + k0 + quad * 8;
            bh[nt] = *(const short8*)(Whg + wo);
            bl[nt] = *(const short8*)(Wlg + wo);
        }
        for (int mt = 0; mt < nm; mt++) {
            int xo = ((m0 + mt) * 16 + r16) * 40 + quad * 8;
            short8 ah = *(const short8*)&Xh[xo];
            short8 al = *(const short8*)&Xl[xo];
            #pragma unroll
            for (int nt = 0; nt < 2; nt++) {
                acc[mt][nt] = __builtin_amdgcn_mfma_f32_16x16x32_bf16(ah, bh[nt], acc[mt][nt], 0, 0, 0);
                acc[mt][nt] = __builtin_amdgcn_mfma_f32_16x16x32_bf16(ah, bl[nt], acc[mt][nt], 0, 0, 0);
                acc[mt][nt] = __builtin_amdgcn_mfma_f32_16x16x32_bf16(al, bh[nt], acc[mt][nt], 0, 0, 0);
            }
        }
    }
    __syncthreads();

    // ---- epilogue A: Y -> LDS split bf16, [n_local][k=m] ----
    for (int mt = 0; mt < nm; mt++) {
        #pragma unroll
        for (int nt = 0; nt < 2; nt++) {
            short4v yh4, yl4;
            #pragma unroll
            for (int rr = 0; rr < 4; rr++) {
                BfPair p = split1(acc[mt][nt][rr]);
                yh4[rr] = p.h; yl4[rr] = p.l;
            }
            int off = (nt * 16 + r16) * 136 + (m0 + mt) * 16 + quad * 4;
            *(short4v*)&Yh[off] = yh4;
            *(short4v*)&Yl[off] = yl4;
            acc[mt][nt] = (floatx4)0.f;
        }
    }
    __syncthreads();

    // ---- phase B: Z = relu(S @ Y + b)  (no barriers; Y read-only) ----
    const short* Sgh = Sh + (size_t)g * 112 * 128;
    const short* Sgl = Sl + (size_t)g * 112 * 128;
    #pragma unroll
    for (int c = 0; c < 4; c++) {
        const int k0 = c << 5;
        short8 bh[2], bl[2];
        #pragma unroll
        for (int nt = 0; nt < 2; nt++) {
            int yo = (nt * 16 + r16) * 136 + k0 + quad * 8;
            bh[nt] = *(const short8*)&Yh[yo];
            bl[nt] = *(const short8*)&Yl[yo];
        }
        for (int mt = 0; mt < nm; mt++) {
            size_t so = (size_t)((m0 + mt) * 16 + r16) * 128 + k0 + quad * 8;
            short8 ah = *(const short8*)(Sgh + so);
            short8 al = *(const short8*)(Sgl + so);
            #pragma unroll
            for (int nt = 0; nt < 2; nt++) {
                acc[mt][nt] = __builtin_amdgcn_mfma_f32_16x16x32_bf16(ah, bh[nt], acc[mt][nt], 0, 0, 0);
                acc[mt][nt] = __builtin_amdgcn_mfma_f32_16x16x32_bf16(ah, bl[nt], acc[mt][nt], 0, 0, 0);
                acc[mt][nt] = __builtin_amdgcn_mfma_f32_16x16x32_bf16(al, bh[nt], acc[mt][nt], 0, 0, 0);
            }
        }
    }

    #pragma unroll
    for (int nt = 0; nt < 2; nt++) {
        float bv = bias[cbase + nt * 16 + r16];
        for (int mt = 0; mt < nm; mt++) {
            #pragma unroll
            for (int rr = 0; rr < 4; rr++) {
                int i = (m0 + mt) * 16 + quad * 4 + rr;
                if (i < A)
                    Z[((size_t)g * A + i) * H + cbase + nt * 16 + r16] =
                        fmaxf(0.f, acc[mt][nt][rr] + bv);
            }
        }
    }
}

// ---------------------------------------------------------------------------
// k_conv: fused conv1(1x3)+relu+conv2(1x3). 4 cols/lane, full c-loop/wave.
// No LDS: weights via wave-uniform loads from wpack (scalar path).
// 1600 blocks x 256 thr = 6400 waves.
// ---------------------------------------------------------------------------
__global__ __launch_bounds__(256) void k_conv(const float* __restrict__ h3,
                                              const float* __restrict__ wpack,
                                              float* __restrict__ out) {
    const int t = threadIdx.x;
    const int wave = t >> 6, lane = t & 63;
    const int n = blockIdx.x * 8 + wave * 2 + (lane >> 5);
    const int q = lane & 31;
    const int j0 = q * 4;
    const float* hr = h3 + (size_t)n * H;

    float hh[8];   // h[j0-2 .. j0+5], zero-padded (conv1 padding)
    if (q == 0) {
        float4 a  = *(const float4*)(hr);
        float2 b2 = *(const float2*)(hr + 4);
        hh[0] = 0.f;  hh[1] = 0.f;  hh[2] = a.x;  hh[3] = a.y;
        hh[4] = a.z;  hh[5] = a.w;  hh[6] = b2.x; hh[7] = b2.y;
    } else if (q == 31) {
        float2 b2 = *(const float2*)(hr + 122);
        float4 a  = *(const float4*)(hr + 124);
        hh[0] = b2.x; hh[1] = b2.y; hh[2] = a.x;  hh[3] = a.y;
        hh[4] = a.z;  hh[5] = a.w;  hh[6] = 0.f;  hh[7] = 0.f;
    } else {
        float4 a  = *(const float4*)(hr + j0 - 2);
        float4 b4 = *(const float4*)(hr + j0 + 2);
        hh[0] = a.x;  hh[1] = a.y;  hh[2] = a.z;  hh[3] = a.w;
        hh[4] = b4.x; hh[5] = b4.y; hh[6] = b4.z; hh[7] = b4.w;
    }
    const float mlo = (q == 0)  ? 0.f : 1.f;   // conv2 pad: T[-1]=0
    const float mhi = (q == 31) ? 0.f : 1.f;   // T[128]=0

    float acc[4] = {0.f, 0.f, 0.f, 0.f};
    #pragma unroll 8
    for (int c = 0; c < H; c++) {
        const float* wp = wpack + c * 8;   // wave-uniform -> s_load
        float w0 = wp[0], w1 = wp[1], w2 = wp[2], b = wp[3];
        float v0 = wp[4], v1 = wp[5], v2 = wp[6];
        float tt[6];   // conv1 output at j = j0-1+m
        #pragma unroll
        for (int m = 0; m < 6; m++)
            tt[m] = fmaxf(0.f, fmaf(w2, hh[m + 2],
                               fmaf(w1, hh[m + 1],
                               fmaf(w0, hh[m], b))));
        tt[0] *= mlo;
        tt[5] *= mhi;
        #pragma unroll
        for (int p = 0; p < 4; p++)
            acc[p] = fmaf(v0, tt[p],
                     fmaf(v1, tt[p + 1],
                     fmaf(v2, tt[p + 2], acc[p])));
    }
    const float c2b = wpack[7];
    *(float4*)(out + (size_t)n * H + j0) =
        make_float4(acc[0] + c2b, acc[1] + c2b, acc[2] + c2b, acc[3] + c2b);
}

// ---------------------------------------------------------------------------
extern "C" void kernel_launch(void* const* d_in, const int* in_sizes, int n_in,
                              void* d_out, int out_size, void* d_ws, size_t ws_size,
                              hipStream_t stream) {
    const float* x   = (const float*)d_in[0];
    const float* W1  = (const float*)d_in[1];
    const float* b1  = (const float*)d_in[2];
    const float* W2  = (const float*)d_in[3];
    const float* b2  = (const float*)d_in[4];
    const float* W3  = (const float*)d_in[5];
    const float* b3  = (const float*)d_in[6];
    const float* cw1 = (const float*)d_in[7];
    const float* cb1 = (const float*)d_in[8];
    const float* cw2 = (const float*)d_in[9];
    const float* cb2 = (const float*)d_in[10];
    float* out = (float*)d_out;

    // ws carve-up
    short* Sh = (short*)d_ws;                       // G*112*128 = 1,835,008
    short* Sl = Sh + (size_t)G * 112 * 128;
    short* Wh = Sl + (size_t)G * 112 * 128;         // 3*128*160 = 61,440
    short* Wl = Wh + 3 * 128 * 160;
    float* wpack = (float*)(Wl + 3 * 128 * 160);    // 1024 floats
    float* bufA  = wpack + 1024;                    // NROWS*H fp32
    float* bufB  = bufA + (size_t)NROWS * H;

    k_prep<<<27, 256, 0, stream>>>(W1, W2, W3, cw1, cb1, cw2, cb2, Wh, Wl, wpack);
    k_nadj<<<G, 256, 0, stream>>>(x, Sh, Sl);

    k_layer<<<dim3(G, 4), 256, 0, stream>>>(Sh, Sl, Wh,             Wl,             x,    b1, bufA, K1);
    k_layer<<<dim3(G, 4), 256, 0, stream>>>(Sh, Sl, Wh + 128 * 160, Wl + 128 * 160, bufA, b2, bufB, H);
    k_layer<<<dim3(G, 4), 256, 0, stream>>>(Sh, Sl, Wh + 256 * 160, Wl + 256 * 160, bufB, b3, bufA, H);

    k_conv<<<NROWS / 8, 256, 0, stream>>>(bufA, wpack, out);
}